// Round 1
// baseline (100.653 us; speedup 1.0000x reference)
//
#include <hip/hip_runtime.h>

// ALNN layer: B=64, K=13, L=200, D=64, fp32. Two-stage restructure.
//
// Stage 1: block = (batch-group of 8) x (l-chunk of 4), loops ALL 13 k.
//   - X/T/M/DT read exactly once from HBM (was 13x: 162.5 MB -> 12.5 MB)
//   - weights read once per batch-GROUP   (was 32x: 128 MB  -> 32 MB)
//   Partial L-sums (per chunk) go to d_ws: [NC][B][K][D] = 10.65 MB.
// Stage 2: reduce the 50 chunk-partials, add 200*b_v, relu, write out.
//   Deterministic (no atomics), all of d_ws's read range is written first.

#define NB 64
#define NK 13
#define NL 200
#define ND 64
#define ND4 16        // float4s per d-row
#define GB 8          // batches per block
#define LC 4          // l per chunk
#define NC (NL / LC)  // 50 chunks

__global__ __launch_bounds__(256) void alnn_stage1(
    const float* __restrict__ X, const float* __restrict__ T,
    const float* __restrict__ M, const float* __restrict__ DT,
    const float* __restrict__ alpha, const float* __restrict__ w_v,
    const float* __restrict__ w_t, const float* __restrict__ b_t,
    float4* __restrict__ part)
{
    // Grid = 512 (112 no-op). Decode so the 8 batch-group blocks sharing one
    // l-chunk's weights satisfy bid % 8 == c % 8 -> same XCD (round-robin
    // heuristic): the weight slice is fetched into one L2, not eight.
    const int bid = blockIdx.x;
    const int xcd = bid & 7;
    const int j   = bid >> 3;                 // 0..63
    const int c   = ((j >> 3) << 3) | xcd;    // l-chunk 0..63
    if (c >= NC) return;
    const int bg  = j & 7;                    // batch group 0..7

    const int tid = threadIdx.x;
    const int dq  = tid & 15;                 // float4 index along d
    const int s   = tid >> 4;                 // 0..15
    const int bb  = s >> 1;                   // batch within group 0..7
    const int lh  = s & 1;                    // l-half of the chunk
    const int b   = (bg << 3) + bb;
    const int la  = c * LC + (lh << 1);       // first of this thread's 2 l
    const int d0  = dq << 2;

    const float4* X4  = (const float4*)X;
    const float4* T4  = (const float4*)T;
    const float4* M4  = (const float4*)M;
    const float4* DT4 = (const float4*)DT;
    const float4* WT4 = (const float4*)w_t;   // f4 idx = (k*NL+l)*ND + d
    const float4* BT4 = (const float4*)b_t;   // f4 idx = (k*NL+l)*ND4 + dq
    const float4* WV4 = (const float4*)w_v;

    // inputs: loaded ONCE, live in registers across the whole k-loop
    const int io0 = (b * NL + la) * ND4 + dq;
    const int io1 = io0 + ND4;
    const float4 xA = X4[io0],  xB = X4[io1];
    const float4 tA = T4[io0],  tB = T4[io1];
    const float4 mA = M4[io0],  mB = M4[io1];
    const float4 dA = DT4[io0], dB = DT4[io1];

    float4 acc[NK];
    #pragma unroll
    for (int k = 0; k < NK; ++k) acc[k] = make_float4(0.f, 0.f, 0.f, 0.f);

#define COMP(c_, wt, xv, tv, mv, dv, bt4, wv4, A) {                       \
        const float dist  = fabsf(tv.c_ - reft);                          \
        const float inten = fmaxf(xv.c_ * __expf(-a * dist), 0.f);        \
        const float sf = wt.x * xv.c_ + wt.y * dv.c_ + wt.z * inten +     \
                         wt.w * mv.c_ + 4.f * bt4.c_;                     \
        A.c_ = fmaf(wv4.c_, fmaxf(sf, 0.f), A.c_);                        \
    }

    // Fully unrolled: keeps acc[k] statically indexed (never scratch).
    #pragma unroll
    for (int k = 0; k < NK; ++k) {
        const float a    = fmaxf(alpha[k], 0.f);
        const float reft = 4.f * (float)k;     // linspace(0,48,13) step = 4
        const int wq = (k * NL + la) * ND4 + dq;
        const int w0 = (k * NL + la) * ND + d0;
        {   // l = la (inputs *A)
            const float4 wt0 = WT4[w0 + 0];
            const float4 wt1 = WT4[w0 + 1];
            const float4 wt2 = WT4[w0 + 2];
            const float4 wt3 = WT4[w0 + 3];
            const float4 bt4 = BT4[wq];
            const float4 wv4 = WV4[wq];
            COMP(x, wt0, xA, tA, mA, dA, bt4, wv4, acc[k])
            COMP(y, wt1, xA, tA, mA, dA, bt4, wv4, acc[k])
            COMP(z, wt2, xA, tA, mA, dA, bt4, wv4, acc[k])
            COMP(w, wt3, xA, tA, mA, dA, bt4, wv4, acc[k])
        }
        {   // l = la+1 (inputs *B)
            const float4 wt0 = WT4[w0 + ND + 0];
            const float4 wt1 = WT4[w0 + ND + 1];
            const float4 wt2 = WT4[w0 + ND + 2];
            const float4 wt3 = WT4[w0 + ND + 3];
            const float4 bt4 = BT4[wq + ND4];
            const float4 wv4 = WV4[wq + ND4];
            COMP(x, wt0, xB, tB, mB, dB, bt4, wv4, acc[k])
            COMP(y, wt1, xB, tB, mB, dB, bt4, wv4, acc[k])
            COMP(z, wt2, xB, tB, mB, dB, bt4, wv4, acc[k])
            COMP(w, wt3, xB, tB, mB, dB, bt4, wv4, acc[k])
        }
    }
#undef COMP

    // fold the two l-halves: partner lane = tid ^ 16 (same wave64)
    #pragma unroll
    for (int k = 0; k < NK; ++k) {
        acc[k].x += __shfl_xor(acc[k].x, 16);
        acc[k].y += __shfl_xor(acc[k].y, 16);
        acc[k].z += __shfl_xor(acc[k].z, 16);
        acc[k].w += __shfl_xor(acc[k].w, 16);
    }

    // both halves hold the full chunk sum; split the 13 k-writes between them
    const int pb = ((c * NB + b) * NK) * ND4 + dq;
    #pragma unroll
    for (int k = 0; k < NK; ++k) {
        if ((k < 7) == (lh == 0))
            part[pb + k * ND4] = acc[k];
    }
}

__global__ __launch_bounds__(256) void alnn_stage2(
    const float4* __restrict__ part, const float* __restrict__ b_v,
    float4* __restrict__ out)
{
    const int tid = blockIdx.x * 256 + threadIdx.x;  // 0..13311 (exact)
    const int dq  = tid & 15;
    const int bk  = tid >> 4;        // b*NK + k
    const int k   = bk % NK;

    float4 s = make_float4(0.f, 0.f, 0.f, 0.f);
    #pragma unroll 5
    for (int c = 0; c < NC; ++c) {   // consecutive threads coalesced per plane
        const float4 p = part[(c * NB * NK + bk) * ND4 + dq];
        s.x += p.x; s.y += p.y; s.z += p.z; s.w += p.w;
    }
    const float4 bv = ((const float4*)b_v)[k * ND4 + dq];
    float4 r;
    r.x = fmaxf(s.x + 200.f * bv.x, 0.f);
    r.y = fmaxf(s.y + 200.f * bv.y, 0.f);
    r.z = fmaxf(s.z + 200.f * bv.z, 0.f);
    r.w = fmaxf(s.w + 200.f * bv.w, 0.f);
    out[tid] = r;                    // out f4 idx = (b*NK+k)*ND4+dq = tid
}

extern "C" void kernel_launch(void* const* d_in, const int* in_sizes, int n_in,
                              void* d_out, int out_size, void* d_ws, size_t ws_size,
                              hipStream_t stream) {
    const float* X     = (const float*)d_in[0];
    const float* T     = (const float*)d_in[1];
    const float* M     = (const float*)d_in[2];
    const float* DT    = (const float*)d_in[3];
    const float* alpha = (const float*)d_in[4];
    const float* w_v   = (const float*)d_in[5];
    const float* w_t   = (const float*)d_in[6];
    const float* b_v   = (const float*)d_in[7];
    const float* b_t   = (const float*)d_in[8];

    float4* part = (float4*)d_ws;    // needs 10.65 MB; ws is 256 MiB

    alnn_stage1<<<512, 256, 0, stream>>>(X, T, M, DT, alpha, w_v, w_t, b_t, part);
    alnn_stage2<<<(NB * NK * ND4) / 256, 256, 0, stream>>>(part, b_v, (float4*)d_out);
}